// Round 18
// baseline (204.876 us; speedup 1.0000x reference)
//
#include <hip/hip_runtime.h>
#include <stdint.h>

// ---------------------------------------------------------------------------
// MultiHeadAttention fwd: B=4 S=2048 D=1024 H=16 DH=64, fp32 in/out.
// Pipeline: cast->bf16 (weights only) | QKV GEMM (256x384 k-slice, 1-round;
//           A staged DIRECTLY from fp32 x via reg-stage+ds_write — x-cast
//           kernel leg eliminated; v-part written in vT layout via per-wave
//           LDS transpose bounce) | flash attention (r16: causal, paired
//           q-tiles, dbuf, in-reg softmax + defer-max, setprio) |
//           out GEMM (256x128, 1-round).
// r17 lesson: joint-PV (V-read sharing) null -> attn not LDS-read-bound;
// reverted. r15 lesson: transposed global writes must bounce through LDS.
// GEMM schedule frozen (r7-r14 falsified schedule/depth/occupancy levers).
// ---------------------------------------------------------------------------

typedef __bf16 bf16;
typedef __attribute__((ext_vector_type(4))) __bf16 bf16x4;
typedef __attribute__((ext_vector_type(8))) __bf16 bf16x8;
typedef __attribute__((ext_vector_type(4))) float f32x4;
typedef __attribute__((ext_vector_type(16))) float f32x16;

#define MFMA16(a, b, c) __builtin_amdgcn_mfma_f32_16x16x32_bf16((a), (b), (c), 0, 0, 0)
#define MFMA32(a, b, c) __builtin_amdgcn_mfma_f32_32x32x16_bf16((a), (b), (c), 0, 0, 0)

#if __has_builtin(__builtin_amdgcn_exp2f)
#define EXP2F(x) __builtin_amdgcn_exp2f(x)
#else
#define EXP2F(x) exp2f(x)
#endif

#define GLOAD_LDS16(gp, lp)                                                    \
  __builtin_amdgcn_global_load_lds(                                            \
      (__attribute__((address_space(1))) void*)(gp),                           \
      (__attribute__((address_space(3))) void*)(lp), 16, 0, 0)

#define SB   2048
#define D3   3072
#define DD   1024
#define QSCALE 0.18033688011112042f   // 1/sqrt(64) * log2(e)

// ---------------------------------------------------------------------------
// fp32->bf16 casts for the two weight matrices only (x handled in-GEMM).
// ---------------------------------------------------------------------------
__global__ __launch_bounds__(256) void cast2_kernel(
    const float* __restrict__ w1, const float* __restrict__ w2,
    bf16* __restrict__ w1b, bf16* __restrict__ w2b) {
  const int stride = gridDim.x * blockDim.x;
  const int gid = blockIdx.x * blockDim.x + threadIdx.x;
  auto cvt = [](const float* in, bf16* out, int i) {
    float4 v = ((const float4*)in)[i];
    bf16x4 p;
    p[0] = (bf16)v.x; p[1] = (bf16)v.y; p[2] = (bf16)v.z; p[3] = (bf16)v.w;
    *(bf16x4*)(out + (size_t)i * 4) = p;
  };
  for (int i = gid; i < 786432; i += stride) cvt(w1, w1b, i);
  for (int i = gid; i < 262144; i += stride) cvt(w2, w2b, i);
}

// ---------------------------------------------------------------------------
// k-slice GEMM (r9/r16-verified schedule): C[m,n] = sum_k A·Bw^T + bias.
// 512 thr = 8 waves (WM x WN), BM = WM*FM*32, BN = WN*FN*32, BK=64.
// OUTMODE 1 (QKV): A comes from FP32 x — per tile each thread loads 8
// float4 (linear global addrs) at loop top, converts and ds_writes 16B to
// the swizzled LDS slot just before __syncthreads (T14 split: HBM latency
// hides under the tile's MFMA work; barrier drains vmcnt+lgkmcnt so the
// r7 handshake proof is unchanged). B stays on global_load_lds DMA.
// Epilogue: q cols scaled -> qkv; k -> qkv; v cols (>=2048) -> vT via
// per-wave LDS transpose bounce (coalesced 16B/lane stores).
// OUTMODE 0 (proj): bf16 A via DMA, fp32 out.
// Swizzle: LDS rows 128B; chunk16 c holds global chunk c^(row&7); reads
// XOR back. MFMA32 frags: row|col=lane&31, k-half=lane>>5; C/D col=lane&31,
// row=(e&3)+8*(e>>2)+4*(lane>>5).
// ---------------------------------------------------------------------------
template <int OUTMODE, int WM, int WN, int FM, int FN>
__global__ __launch_bounds__(512, 1) void gemmks_kernel(
    const bf16* __restrict__ A, const float* __restrict__ Axf,
    const bf16* __restrict__ Bw, const float* __restrict__ bias,
    void* __restrict__ Cout, bf16* __restrict__ VtOut,
    int M, int N, int K, int NBn) {
  constexpr int BM = WM * FM * 32, BN = WN * FN * 32;
  constexpr int NRA = BM / 64, NRB = BN / 64;
  __shared__ __attribute__((aligned(16))) bf16 As[2][BM * 64];
  __shared__ __attribute__((aligned(16))) bf16 Bs[2][BN * 64];
  const int tid = threadIdx.x;
  const int w = tid >> 6, l = tid & 63;
  const int lr = l & 31, lh = l >> 5;
  const int wm = w / WN, wn = w % WN;
  const int nwg = gridDim.x;
  const int sw = ((int)blockIdx.x % 8) * (nwg / 8) + (int)blockIdx.x / 8;
  const int bn = sw % NBn, bm = sw / NBn;
  const int m0 = bm * BM, n0 = bn * BN;
  const int NT = K >> 6;

  const int srow = l >> 3;
  const int scol = ((l & 7) ^ srow) << 3;

  float4 ar[NRA][2];  // in-flight fp32 A rows (OUTMODE 1)

  auto loadA = [&](int kt) {        // issue 8 dwordx4 loads (fp32 x)
#pragma unroll
    for (int j = 0; j < NRA; ++j) {
      const int rb = j * 64 + w * 8 + srow;
      const float* src = Axf + (size_t)(m0 + rb) * K + kt * 64 + scol;
      ar[j][0] = *(const float4*)src;
      ar[j][1] = *(const float4*)(src + 4);
    }
  };
  auto writeA = [&](int buf) {      // convert + ds_write to swizzled slot
#pragma unroll
    for (int j = 0; j < NRA; ++j) {
      bf16x8 v;
      v[0] = (bf16)ar[j][0].x; v[1] = (bf16)ar[j][0].y;
      v[2] = (bf16)ar[j][0].z; v[3] = (bf16)ar[j][0].w;
      v[4] = (bf16)ar[j][1].x; v[5] = (bf16)ar[j][1].y;
      v[6] = (bf16)ar[j][1].z; v[7] = (bf16)ar[j][1].w;
      *(bf16x8*)((char*)&As[buf][0] + j * 8192 + w * 1024 + l * 16) = v;
    }
  };
  auto stageA_dma = [&](int buf, int kt) {
#pragma unroll
    for (int j = 0; j < NRA; ++j) {
      const int rb = j * 64 + w * 8 + srow;
      GLOAD_LDS16(A + (size_t)(m0 + rb) * K + kt * 64 + scol,
                  (char*)&As[buf][0] + j * 8192 + w * 1024);
    }
  };
  auto stageB = [&](int buf, int kt) {
#pragma unroll
    for (int j = 0; j < NRB; ++j) {
      const int rb = j * 64 + w * 8 + srow;
      GLOAD_LDS16(Bw + (size_t)(n0 + rb) * K + kt * 64 + scol,
                  (char*)&Bs[buf][0] + j * 8192 + w * 1024);
    }
  };

  f32x16 acc[FM][FN] = {};

  if constexpr (OUTMODE == 1) { loadA(0); writeA(0); }
  else                        { stageA_dma(0, 0); }
  stageB(0, 0);
  __syncthreads();

  for (int T = 0; T < NT; ++T) {
    const int buf = T & 1;
    if (T + 1 < NT) {
      if constexpr (OUTMODE == 1) loadA(T + 1);   // overlaps tile compute
      else                        stageA_dma(buf ^ 1, T + 1);
      stageB(buf ^ 1, T + 1);
    }
#pragma unroll
    for (int ks = 0; ks < 4; ++ks) {
      bf16x8 aF[FM], bF[FN];
#pragma unroll
      for (int ti = 0; ti < FM; ++ti) {
        const int r = wm * (FM * 32) + ti * 32 + lr;
        aF[ti] = *(const bf16x8*)((const char*)&As[buf][0] + r * 128 +
                                  (((ks * 2 + lh) ^ (lr & 7)) << 4));
      }
#pragma unroll
      for (int tj = 0; tj < FN; ++tj) {
        const int r = wn * (FN * 32) + tj * 32 + lr;
        bF[tj] = *(const bf16x8*)((const char*)&Bs[buf][0] + r * 128 +
                                  (((ks * 2 + lh) ^ (lr & 7)) << 4));
      }
      __builtin_amdgcn_s_setprio(1);
#pragma unroll
      for (int ti = 0; ti < FM; ++ti)
#pragma unroll
        for (int tj = 0; tj < FN; ++tj)
          acc[ti][tj] = MFMA32(aF[ti], bF[tj], acc[ti][tj]);
      __builtin_amdgcn_s_setprio(0);
    }
    if (T + 1 < NT) {
      if constexpr (OUTMODE == 1) writeA(buf ^ 1);  // loads landed by now
    }
    __syncthreads();  // drains vmcnt(B dma, A loads) + lgkmcnt(A ds_writes)
  }

  // ---- epilogue (per-wave private LDS slice reused for V transpose bounce)
#pragma unroll
  for (int ti = 0; ti < FM; ++ti) {
    const int r0 = m0 + wm * (FM * 32) + ti * 32 + 4 * lh;
#pragma unroll
    for (int tj = 0; tj < FN; ++tj) {
      const int colbase = n0 + wn * (FN * 32) + tj * 32;
      const int col = colbase + lr;
      const float bv = bias[col];
      if (OUTMODE == 1 && colbase >= 2 * DD) {
        bf16* lt = (bf16*)((char*)&As[0][0] + w * 2560);   // [32][40] bf16
        asm volatile("s_waitcnt lgkmcnt(0)" ::: "memory");
        __builtin_amdgcn_sched_barrier(0);
#pragma unroll
        for (int e = 0; e < 16; ++e) {
          const int row = (e & 3) + 8 * (e >> 2) + 4 * lh; // 0..31
          lt[lr * 40 + row] = (bf16)(acc[ti][tj][e] + bv);
        }
        asm volatile("s_waitcnt lgkmcnt(0)" ::: "memory");
        __builtin_amdgcn_sched_barrier(0);
        const int colloc = l >> 1;
        const int hd = colbase + colloc - 2 * DD;
        const int sbase = m0 + wm * (FM * 32) + ti * 32;
        const size_t gb = ((size_t)((sbase >> 11) * 1024 + hd)) * SB +
                          (sbase & 2047) + (l & 1) * 8;
#pragma unroll
        for (int it2 = 0; it2 < 2; ++it2) {
          bf16x8 vv = *(const bf16x8*)&lt[colloc * 40 + it2 * 16 + (l & 1) * 8];
          *(bf16x8*)(VtOut + gb + it2 * 16) = vv;
        }
      } else {
#pragma unroll
        for (int e = 0; e < 16; ++e) {
          const int row = r0 + (e & 3) + 8 * (e >> 2);
          float v = acc[ti][tj][e] + bv;
          if (OUTMODE == 1) {
            if (col < DD) v *= QSCALE;
            ((bf16*)Cout)[(size_t)row * N + col] = (bf16)v;
          } else {
            ((float*)Cout)[(size_t)row * N + col] = v;
          }
        }
      }
    }
  }
}

// ---------------------------------------------------------------------------
// Causal flash attention (r16/r13: paired q-tiles, dbuf, in-reg softmax,
// defer-max, setprio around MFMA clusters).
// ---------------------------------------------------------------------------
__global__ __launch_bounds__(256, 2) void attn_kernel(
    const bf16* __restrict__ qkv, const bf16* __restrict__ vT,
    bf16* __restrict__ o) {
  __shared__ __attribute__((aligned(16))) bf16 Kt[2][128 * 64];
  __shared__ __attribute__((aligned(16))) bf16 Vt[2][64 * 128];
  const int tid = threadIdx.x;
  const int w = tid >> 6, l = tid & 63;
  const int c = l & 15, g = l >> 4;
  const int pair = blockIdx.x >> 6, bh = blockIdx.x & 63;
  const int b = bh >> 4, h = bh & 15;
  const int qtA = pair, qtB = 15 - pair;
  const int swz = (c & 7) << 4;

  const bf16* qg = qkv + (size_t)(b * SB) * D3 + h * 64;

  auto stage = [&](int kt, int buf) {
#pragma unroll
    for (int j = 0; j < 4; ++j) {
      const int row = w * 32 + j * 8 + (l >> 3);
      const int cs = ((l & 7) ^ (row & 7)) << 3;
      GLOAD_LDS16(qkv + (size_t)(b * SB + kt * 128 + row) * D3 + DD + h * 64 + cs,
                  (char*)&Kt[buf][0] + w * 4096 + j * 1024);
    }
#pragma unroll
    for (int j = 0; j < 4; ++j) {
      const int row = w * 16 + j * 4 + (l >> 4);
      const int cs = ((l & 15) ^ (row & 7)) << 3;
      GLOAD_LDS16(vT + (size_t)(bh * 64 + row) * SB + kt * 128 + cs,
                  (char*)&Vt[buf][0] + w * 4096 + j * 1024);
    }
  };

  stage(0, 0);

  bf16x8 qfA[2][2], qfB[2][2];
#pragma unroll
  for (int mi = 0; mi < 2; ++mi)
#pragma unroll
    for (int dk = 0; dk < 2; ++dk) {
      qfA[mi][dk] = *(const bf16x8*)(qg + (size_t)(qtA * 128 + w * 32 + mi * 16 + c) * D3 + dk * 32 + g * 8);
      qfB[mi][dk] = *(const bf16x8*)(qg + (size_t)(qtB * 128 + w * 32 + mi * 16 + c) * D3 + dk * 32 + g * 8);
    }

  f32x4 ofA[2][4] = {}, ofB[2][4] = {};
  float mA[2] = {-1e30f, -1e30f}, lA[2] = {0.f, 0.f};
  float mB[2] = {-1e30f, -1e30f}, lB[2] = {0.f, 0.f};
  const f32x4 zero = {0.f, 0.f, 0.f, 0.f};

  auto process = [&](int kt, int qt, int buf, bf16x8 (&qf)[2][2], float (&m)[2],
                     float (&lsum)[2], f32x4 (&of)[2][4]) {
    f32x4 sf[2][8];
    __builtin_amdgcn_s_setprio(1);
#pragma unroll
    for (int f = 0; f < 8; ++f) {
      const char* kr = (const char*)&Kt[buf][0] + (f * 16 + c) * 128;
      bf16x8 kb0 = *(const bf16x8*)(kr + ((g * 16) ^ swz));
      bf16x8 kb1 = *(const bf16x8*)(kr + ((64 + g * 16) ^ swz));
#pragma unroll
      for (int mi = 0; mi < 2; ++mi) {
        f32x4 t = MFMA16(kb0, qf[mi][0], zero);
        sf[mi][f] = MFMA16(kb1, qf[mi][1], t);
      }
    }
    __builtin_amdgcn_s_setprio(0);

    if (kt == qt) {
#pragma unroll
      for (int mi = 0; mi < 2; ++mi) {
        const int qloc = w * 32 + mi * 16 + c;
#pragma unroll
        for (int f = 0; f < 8; ++f)
#pragma unroll
          for (int r = 0; r < 4; ++r)
            if (f * 16 + 4 * g + r > qloc) sf[mi][f][r] = -1e30f;
      }
    }

    bf16x8 pa[2][4];
#pragma unroll
    for (int mi = 0; mi < 2; ++mi) {
      float pm = -1e30f;
#pragma unroll
      for (int f = 0; f < 8; ++f)
#pragma unroll
        for (int r = 0; r < 4; ++r) pm = fmaxf(pm, sf[mi][f][r]);
      pm = fmaxf(pm, __shfl_xor(pm, 16, 64));
      pm = fmaxf(pm, __shfl_xor(pm, 32, 64));
      if (__any(pm > m[mi] + 8.f)) {
        const float mnew = fmaxf(m[mi], pm);
        const float sc = EXP2F(m[mi] - mnew);
        m[mi] = mnew;
        lsum[mi] *= sc;
#pragma unroll
        for (int di = 0; di < 4; ++di) of[mi][di] *= sc;
      }
      float rs = 0.f;
#pragma unroll
      for (int f = 0; f < 8; ++f)
#pragma unroll
        for (int r = 0; r < 4; ++r) {
          const float pv = EXP2F(sf[mi][f][r] - m[mi]);
          sf[mi][f][r] = pv;
          rs += pv;
        }
      rs += __shfl_xor(rs, 16, 64);
      rs += __shfl_xor(rs, 32, 64);
      lsum[mi] += rs;
#pragma unroll
      for (int t = 0; t < 4; ++t)
#pragma unroll
        for (int s = 0; s < 4; ++s) {
          pa[mi][t][s]     = (bf16)sf[mi][2 * t][s];
          pa[mi][t][4 + s] = (bf16)sf[mi][2 * t + 1][s];
        }
    }

    __builtin_amdgcn_s_setprio(1);
#pragma unroll
    for (int di = 0; di < 4; ++di) {
      const char* vrow = (const char*)&Vt[buf][0] + (di * 16 + c) * 256;
#pragma unroll
      for (int t = 0; t < 4; ++t) {
        bf16x4 v1 = *(const bf16x4*)(vrow + ((64 * t + 8 * g) ^ swz));
        bf16x4 v2 = *(const bf16x4*)(vrow + ((64 * t + 32 + 8 * g) ^ swz));
        bf16x8 va;
#pragma unroll
        for (int s = 0; s < 4; ++s) { va[s] = v1[s]; va[4 + s] = v2[s]; }
#pragma unroll
        for (int mi = 0; mi < 2; ++mi)
          of[mi][di] = MFMA16(va, pa[mi][t], of[mi][di]);
      }
    }
    __builtin_amdgcn_s_setprio(0);
  };

  __syncthreads();

  int buf = 0;
  for (int kt = 0; kt <= qtB; ++kt) {
    if (kt < qtB) stage(kt + 1, buf ^ 1);
    if (kt <= qtA) process(kt, qtA, buf, qfA, mA, lA, ofA);
    process(kt, qtB, buf, qfB, mB, lB, ofB);
    __syncthreads();
    buf ^= 1;
  }

  auto store_tile = [&](int qt, float (&lsum)[2], f32x4 (&of)[2][4]) {
#pragma unroll
    for (int mi = 0; mi < 2; ++mi) {
      const float inv = 1.0f / lsum[mi];
      const size_t row = (size_t)(b * SB + qt * 128 + w * 32 + mi * 16 + c);
#pragma unroll
      for (int di = 0; di < 4; ++di) {
        bf16x4 st;
#pragma unroll
        for (int r = 0; r < 4; ++r) st[r] = (bf16)(of[mi][di][r] * inv);
        *(bf16x4*)(o + row * DD + h * 64 + di * 16 + 4 * g) = st;
      }
    }
  };
  store_tile(qtA, lA, ofA);
  store_tile(qtB, lB, ofB);
}

// ---------------------------------------------------------------------------
extern "C" void kernel_launch(void* const* d_in, const int* in_sizes, int n_in,
                              void* d_out, int out_size, void* d_ws, size_t ws_size,
                              hipStream_t stream) {
  const float* x  = (const float*)d_in[0];
  const float* w1 = (const float*)d_in[1];
  const float* b1 = (const float*)d_in[2];
  const float* w2 = (const float*)d_in[3];
  const float* b2 = (const float*)d_in[4];
  float* out = (float*)d_out;

  bf16* xb   = (bf16*)d_ws;                          // unused (kept for layout)
  bf16* w1b  = xb   + (size_t)8  * 1024 * 1024;
  bf16* w2b  = w1b  + (size_t)3  * 1024 * 1024;
  bf16* qkvb = w2b  + (size_t)1  * 1024 * 1024;
  bf16* vT   = qkvb + (size_t)8192 * 3072;
  bf16* ob   = vT   + (size_t)8  * 1024 * 1024;

  cast2_kernel<<<512, 256, 0, stream>>>(w1, w2, w1b, w2b);

  // QKV: 256x384 tiles -> grid 256 = one round. A staged from fp32 x
  // in-kernel; v-part -> vT via LDS transpose bounce.
  gemmks_kernel<1, 2, 4, 4, 3><<<256, 512, 0, stream>>>(
      nullptr, x, w1b, b1, qkvb, vT, 8192, 3072, 1024, 8);
  attn_kernel<<<512, 256, 0, stream>>>(qkvb, vT, ob);
  // proj: 256x128 tiles -> grid 256 = one round (bf16 A via DMA).
  gemmks_kernel<0, 4, 2, 2, 2><<<256, 512, 0, stream>>>(
      ob, nullptr, w2b, b2, out, nullptr, 8192, 1024, 1024, 8);
}

// Round 19
// 153.300 us; speedup vs baseline: 1.3364x; 1.3364x over previous
//
#include <hip/hip_runtime.h>
#include <stdint.h>

// ---------------------------------------------------------------------------
// MultiHeadAttention fwd: B=4 S=2048 D=1024 H=16 DH=64, fp32 in/out.
// Pipeline: fused cast->bf16 | QKV GEMM (256x384 k-slice, 1-round; v-part
//           written in vT layout via per-wave LDS transpose bounce — vtrans
//           kernel eliminated, writes coalesced 16B/lane) | flash attention
//           (causal, paired q-tiles, dbuf, in-reg softmax + defer-max,
//           setprio) | out GEMM (256x128, 1-round).
// == r16 verbatim (banked best 154.0us). ==
// Falsified levers (do not retry): 8-phase/depth-3/fat-tile GEMM schedules
// (620-680 TF is this structure's K=1024 ceiling; fat tiles + held operand
// regs spill past ~230 live VGPR — r12/r18), co-residency (r14), joint-PV
// V-read sharing (r17), direct-scatter vT writes (r15), in-GEMM fp32 A
// staging (r18 spill). Wins: in-reg swapped softmax + paired q-tiles,
// dbuf+defer-max, exact-1-round grids, LDS-bounce vT fusion, merged casts.
// ---------------------------------------------------------------------------

typedef __bf16 bf16;
typedef __attribute__((ext_vector_type(4))) __bf16 bf16x4;
typedef __attribute__((ext_vector_type(8))) __bf16 bf16x8;
typedef __attribute__((ext_vector_type(4))) float f32x4;
typedef __attribute__((ext_vector_type(16))) float f32x16;

#define MFMA16(a, b, c) __builtin_amdgcn_mfma_f32_16x16x32_bf16((a), (b), (c), 0, 0, 0)
#define MFMA32(a, b, c) __builtin_amdgcn_mfma_f32_32x32x16_bf16((a), (b), (c), 0, 0, 0)

#if __has_builtin(__builtin_amdgcn_exp2f)
#define EXP2F(x) __builtin_amdgcn_exp2f(x)
#else
#define EXP2F(x) exp2f(x)
#endif

#define GLOAD_LDS16(gp, lp)                                                    \
  __builtin_amdgcn_global_load_lds(                                            \
      (__attribute__((address_space(1))) void*)(gp),                           \
      (__attribute__((address_space(3))) void*)(lp), 16, 0, 0)

#define SB   2048
#define D3   3072
#define DD   1024
#define QSCALE 0.18033688011112042f   // 1/sqrt(64) * log2(e)

// ---------------------------------------------------------------------------
// Fused fp32->bf16 casts: x (2M float4), w1 (768K), w2 (256K) in one launch.
// ---------------------------------------------------------------------------
__global__ __launch_bounds__(256) void cast3_kernel(
    const float* __restrict__ x, const float* __restrict__ w1,
    const float* __restrict__ w2, bf16* __restrict__ xb,
    bf16* __restrict__ w1b, bf16* __restrict__ w2b) {
  const int stride = gridDim.x * blockDim.x;
  const int gid = blockIdx.x * blockDim.x + threadIdx.x;
  auto cvt = [](const float* in, bf16* out, int i) {
    float4 v = ((const float4*)in)[i];
    bf16x4 p;
    p[0] = (bf16)v.x; p[1] = (bf16)v.y; p[2] = (bf16)v.z; p[3] = (bf16)v.w;
    *(bf16x4*)(out + (size_t)i * 4) = p;
  };
  for (int i = gid; i < 2097152; i += stride) cvt(x, xb, i);
  for (int i = gid; i < 786432; i += stride) cvt(w1, w1b, i);
  for (int i = gid; i < 262144; i += stride) cvt(w2, w2b, i);
}

// ---------------------------------------------------------------------------
// k-slice GEMM (r9-verified): C[m,n] = sum_k A[m,k]*Bw[n,k] + bias[n].
// 512 thr = 8 waves (WM x WN), BM = WM*FM*32, BN = WN*FN*32, BK=64.
// Per-wave output (FM*32) x (FN*32) via MFMA32, acc FM x FN x f32x16.
// Per K-tile: stage(T+1) first (overlaps compute), 4 k-slices {ld FM+FN
// unique b128 -> MFMA}, ONE __syncthreads per tile. Grids = exactly one
// round of 256 CUs. Swizzle: LDS rows 128B; chunk16 c holds global chunk
// c^(row&7) via pre-swizzled source; reads XOR back.
// MFMA32 frags: row|col = lane&31, k-half = lane>>5; C/D col=lane&31,
// row=(e&3)+8*(e>>2)+4*(lane>>5).
// OUTMODE 1 (QKV): q cols (<1024) scaled by QSCALE -> qkv; k cols -> qkv;
// v cols (>=2048, whole 32-col sub-tiles) -> vT[(b*1024+hd)*2048+s] via
// per-wave LDS transpose bounce: acc -> lt[32][40] (stride-40 spreads
// banks), wave-local lgkmcnt fences (+sched_barrier, rule #18), then
// 16B/lane col-major stores (2 lanes = one column's 32 consecutive s).
// OUTMODE 0 (proj): fp32 out.
// ---------------------------------------------------------------------------
template <int OUTMODE, int WM, int WN, int FM, int FN>
__global__ __launch_bounds__(512, 1) void gemmks_kernel(
    const bf16* __restrict__ A, const bf16* __restrict__ Bw,
    const float* __restrict__ bias, void* __restrict__ Cout,
    bf16* __restrict__ VtOut, int M, int N, int K, int NBn) {
  constexpr int BM = WM * FM * 32, BN = WN * FN * 32;
  constexpr int NRA = BM / 64, NRB = BN / 64;
  __shared__ __attribute__((aligned(16))) bf16 As[2][BM * 64];
  __shared__ __attribute__((aligned(16))) bf16 Bs[2][BN * 64];
  const int tid = threadIdx.x;
  const int w = tid >> 6, l = tid & 63;
  const int lr = l & 31, lh = l >> 5;
  const int wm = w / WN, wn = w % WN;
  const int nwg = gridDim.x;
  const int sw = ((int)blockIdx.x % 8) * (nwg / 8) + (int)blockIdx.x / 8;
  const int bn = sw % NBn, bm = sw / NBn;
  const int m0 = bm * BM, n0 = bn * BN;
  const int NT = K >> 6;

  const int srow = l >> 3;
  const int scol = ((l & 7) ^ srow) << 3;

  auto stage = [&](int buf, int kt) {
#pragma unroll
    for (int j = 0; j < NRA; ++j) {
      const int rb = j * 64 + w * 8 + srow;
      GLOAD_LDS16(A + (size_t)(m0 + rb) * K + kt * 64 + scol,
                  (char*)&As[buf][0] + j * 8192 + w * 1024);
    }
#pragma unroll
    for (int j = 0; j < NRB; ++j) {
      const int rb = j * 64 + w * 8 + srow;
      GLOAD_LDS16(Bw + (size_t)(n0 + rb) * K + kt * 64 + scol,
                  (char*)&Bs[buf][0] + j * 8192 + w * 1024);
    }
  };

  f32x16 acc[FM][FN] = {};

  stage(0, 0);
  __syncthreads();

  for (int T = 0; T < NT; ++T) {
    const int buf = T & 1;
    if (T + 1 < NT) stage(buf ^ 1, T + 1);
#pragma unroll
    for (int ks = 0; ks < 4; ++ks) {
      bf16x8 aF[FM], bF[FN];
#pragma unroll
      for (int ti = 0; ti < FM; ++ti) {
        const int r = wm * (FM * 32) + ti * 32 + lr;
        aF[ti] = *(const bf16x8*)((const char*)&As[buf][0] + r * 128 +
                                  (((ks * 2 + lh) ^ (lr & 7)) << 4));
      }
#pragma unroll
      for (int tj = 0; tj < FN; ++tj) {
        const int r = wn * (FN * 32) + tj * 32 + lr;
        bF[tj] = *(const bf16x8*)((const char*)&Bs[buf][0] + r * 128 +
                                  (((ks * 2 + lh) ^ (lr & 7)) << 4));
      }
      __builtin_amdgcn_s_setprio(1);
#pragma unroll
      for (int ti = 0; ti < FM; ++ti)
#pragma unroll
        for (int tj = 0; tj < FN; ++tj)
          acc[ti][tj] = MFMA32(aF[ti], bF[tj], acc[ti][tj]);
      __builtin_amdgcn_s_setprio(0);
    }
    __syncthreads();
  }

  // ---- epilogue. After the loop's final barrier, LDS is dead; each wave
  // reuses a PRIVATE 2.5KB slice of As[0] for the V transpose bounce.
#pragma unroll
  for (int ti = 0; ti < FM; ++ti) {
    const int r0 = m0 + wm * (FM * 32) + ti * 32 + 4 * lh;
#pragma unroll
    for (int tj = 0; tj < FN; ++tj) {
      const int colbase = n0 + wn * (FN * 32) + tj * 32;
      const int col = colbase + lr;
      const float bv = bias[col];
      if (OUTMODE == 1 && colbase >= 2 * DD) {
        // V sub-tile (32 cols x 32 s-rows): transpose via per-wave LDS
        bf16* lt = (bf16*)((char*)&As[0][0] + w * 2560);   // [32][40] bf16
        asm volatile("s_waitcnt lgkmcnt(0)" ::: "memory"); // prev reads done
        __builtin_amdgcn_sched_barrier(0);
#pragma unroll
        for (int e = 0; e < 16; ++e) {
          const int row = (e & 3) + 8 * (e >> 2) + 4 * lh; // 0..31
          lt[lr * 40 + row] = (bf16)(acc[ti][tj][e] + bv);
        }
        asm volatile("s_waitcnt lgkmcnt(0)" ::: "memory"); // writes visible
        __builtin_amdgcn_sched_barrier(0);
        const int colloc = l >> 1;                          // 0..31
        const int hd = colbase + colloc - 2 * DD;           // 0..1023
        const int sbase = m0 + wm * (FM * 32) + ti * 32;    // 32-aligned
        const size_t gb = ((size_t)((sbase >> 11) * 1024 + hd)) * SB +
                          (sbase & 2047) + (l & 1) * 8;
#pragma unroll
        for (int it2 = 0; it2 < 2; ++it2) {
          bf16x8 vv = *(const bf16x8*)&lt[colloc * 40 + it2 * 16 + (l & 1) * 8];
          *(bf16x8*)(VtOut + gb + it2 * 16) = vv;
        }
      } else {
#pragma unroll
        for (int e = 0; e < 16; ++e) {
          const int row = r0 + (e & 3) + 8 * (e >> 2);
          float v = acc[ti][tj][e] + bv;
          if (OUTMODE == 1) {
            if (col < DD) v *= QSCALE;
            ((bf16*)Cout)[(size_t)row * N + col] = (bf16)v;
          } else {
            ((float*)Cout)[(size_t)row * N + col] = v;
          }
        }
      }
    }
  }
}

// ---------------------------------------------------------------------------
// Causal flash attention (r13: paired q-tiles, dbuf, in-reg softmax,
// defer-max, setprio around MFMA clusters).
// ---------------------------------------------------------------------------
__global__ __launch_bounds__(256, 2) void attn_kernel(
    const bf16* __restrict__ qkv, const bf16* __restrict__ vT,
    bf16* __restrict__ o) {
  __shared__ __attribute__((aligned(16))) bf16 Kt[2][128 * 64];
  __shared__ __attribute__((aligned(16))) bf16 Vt[2][64 * 128];
  const int tid = threadIdx.x;
  const int w = tid >> 6, l = tid & 63;
  const int c = l & 15, g = l >> 4;
  const int pair = blockIdx.x >> 6, bh = blockIdx.x & 63;
  const int b = bh >> 4, h = bh & 15;
  const int qtA = pair, qtB = 15 - pair;
  const int swz = (c & 7) << 4;

  const bf16* qg = qkv + (size_t)(b * SB) * D3 + h * 64;

  auto stage = [&](int kt, int buf) {
#pragma unroll
    for (int j = 0; j < 4; ++j) {
      const int row = w * 32 + j * 8 + (l >> 3);
      const int cs = ((l & 7) ^ (row & 7)) << 3;
      GLOAD_LDS16(qkv + (size_t)(b * SB + kt * 128 + row) * D3 + DD + h * 64 + cs,
                  (char*)&Kt[buf][0] + w * 4096 + j * 1024);
    }
#pragma unroll
    for (int j = 0; j < 4; ++j) {
      const int row = w * 16 + j * 4 + (l >> 4);
      const int cs = ((l & 15) ^ (row & 7)) << 3;
      GLOAD_LDS16(vT + (size_t)(bh * 64 + row) * SB + kt * 128 + cs,
                  (char*)&Vt[buf][0] + w * 4096 + j * 1024);
    }
  };

  stage(0, 0);

  bf16x8 qfA[2][2], qfB[2][2];
#pragma unroll
  for (int mi = 0; mi < 2; ++mi)
#pragma unroll
    for (int dk = 0; dk < 2; ++dk) {
      qfA[mi][dk] = *(const bf16x8*)(qg + (size_t)(qtA * 128 + w * 32 + mi * 16 + c) * D3 + dk * 32 + g * 8);
      qfB[mi][dk] = *(const bf16x8*)(qg + (size_t)(qtB * 128 + w * 32 + mi * 16 + c) * D3 + dk * 32 + g * 8);
    }

  f32x4 ofA[2][4] = {}, ofB[2][4] = {};
  float mA[2] = {-1e30f, -1e30f}, lA[2] = {0.f, 0.f};
  float mB[2] = {-1e30f, -1e30f}, lB[2] = {0.f, 0.f};
  const f32x4 zero = {0.f, 0.f, 0.f, 0.f};

  auto process = [&](int kt, int qt, int buf, bf16x8 (&qf)[2][2], float (&m)[2],
                     float (&lsum)[2], f32x4 (&of)[2][4]) {
    f32x4 sf[2][8];
    __builtin_amdgcn_s_setprio(1);
#pragma unroll
    for (int f = 0; f < 8; ++f) {
      const char* kr = (const char*)&Kt[buf][0] + (f * 16 + c) * 128;
      bf16x8 kb0 = *(const bf16x8*)(kr + ((g * 16) ^ swz));
      bf16x8 kb1 = *(const bf16x8*)(kr + ((64 + g * 16) ^ swz));
#pragma unroll
      for (int mi = 0; mi < 2; ++mi) {
        f32x4 t = MFMA16(kb0, qf[mi][0], zero);
        sf[mi][f] = MFMA16(kb1, qf[mi][1], t);
      }
    }
    __builtin_amdgcn_s_setprio(0);

    if (kt == qt) {
#pragma unroll
      for (int mi = 0; mi < 2; ++mi) {
        const int qloc = w * 32 + mi * 16 + c;
#pragma unroll
        for (int f = 0; f < 8; ++f)
#pragma unroll
          for (int r = 0; r < 4; ++r)
            if (f * 16 + 4 * g + r > qloc) sf[mi][f][r] = -1e30f;
      }
    }

    bf16x8 pa[2][4];
#pragma unroll
    for (int mi = 0; mi < 2; ++mi) {
      float pm = -1e30f;
#pragma unroll
      for (int f = 0; f < 8; ++f)
#pragma unroll
        for (int r = 0; r < 4; ++r) pm = fmaxf(pm, sf[mi][f][r]);
      pm = fmaxf(pm, __shfl_xor(pm, 16, 64));
      pm = fmaxf(pm, __shfl_xor(pm, 32, 64));
      if (__any(pm > m[mi] + 8.f)) {
        const float mnew = fmaxf(m[mi], pm);
        const float sc = EXP2F(m[mi] - mnew);
        m[mi] = mnew;
        lsum[mi] *= sc;
#pragma unroll
        for (int di = 0; di < 4; ++di) of[mi][di] *= sc;
      }
      float rs = 0.f;
#pragma unroll
      for (int f = 0; f < 8; ++f)
#pragma unroll
        for (int r = 0; r < 4; ++r) {
          const float pv = EXP2F(sf[mi][f][r] - m[mi]);
          sf[mi][f][r] = pv;
          rs += pv;
        }
      rs += __shfl_xor(rs, 16, 64);
      rs += __shfl_xor(rs, 32, 64);
      lsum[mi] += rs;
#pragma unroll
      for (int t = 0; t < 4; ++t)
#pragma unroll
        for (int s = 0; s < 4; ++s) {
          pa[mi][t][s]     = (bf16)sf[mi][2 * t][s];
          pa[mi][t][4 + s] = (bf16)sf[mi][2 * t + 1][s];
        }
    }

    __builtin_amdgcn_s_setprio(1);
#pragma unroll
    for (int di = 0; di < 4; ++di) {
      const char* vrow = (const char*)&Vt[buf][0] + (di * 16 + c) * 256;
#pragma unroll
      for (int t = 0; t < 4; ++t) {
        bf16x4 v1 = *(const bf16x4*)(vrow + ((64 * t + 8 * g) ^ swz));
        bf16x4 v2 = *(const bf16x4*)(vrow + ((64 * t + 32 + 8 * g) ^ swz));
        bf16x8 va;
#pragma unroll
        for (int s = 0; s < 4; ++s) { va[s] = v1[s]; va[4 + s] = v2[s]; }
#pragma unroll
        for (int mi = 0; mi < 2; ++mi)
          of[mi][di] = MFMA16(va, pa[mi][t], of[mi][di]);
      }
    }
    __builtin_amdgcn_s_setprio(0);
  };

  __syncthreads();

  int buf = 0;
  for (int kt = 0; kt <= qtB; ++kt) {
    if (kt < qtB) stage(kt + 1, buf ^ 1);
    if (kt <= qtA) process(kt, qtA, buf, qfA, mA, lA, ofA);
    process(kt, qtB, buf, qfB, mB, lB, ofB);
    __syncthreads();
    buf ^= 1;
  }

  auto store_tile = [&](int qt, float (&lsum)[2], f32x4 (&of)[2][4]) {
#pragma unroll
    for (int mi = 0; mi < 2; ++mi) {
      const float inv = 1.0f / lsum[mi];
      const size_t row = (size_t)(b * SB + qt * 128 + w * 32 + mi * 16 + c);
#pragma unroll
      for (int di = 0; di < 4; ++di) {
        bf16x4 st;
#pragma unroll
        for (int r = 0; r < 4; ++r) st[r] = (bf16)(of[mi][di][r] * inv);
        *(bf16x4*)(o + row * DD + h * 64 + di * 16 + 4 * g) = st;
      }
    }
  };
  store_tile(qtA, lA, ofA);
  store_tile(qtB, lB, ofB);
}

// ---------------------------------------------------------------------------
extern "C" void kernel_launch(void* const* d_in, const int* in_sizes, int n_in,
                              void* d_out, int out_size, void* d_ws, size_t ws_size,
                              hipStream_t stream) {
  const float* x  = (const float*)d_in[0];
  const float* w1 = (const float*)d_in[1];
  const float* b1 = (const float*)d_in[2];
  const float* w2 = (const float*)d_in[3];
  const float* b2 = (const float*)d_in[4];
  float* out = (float*)d_out;

  bf16* xb   = (bf16*)d_ws;
  bf16* w1b  = xb   + (size_t)8  * 1024 * 1024;
  bf16* w2b  = w1b  + (size_t)3  * 1024 * 1024;
  bf16* qkvb = w2b  + (size_t)1  * 1024 * 1024;
  bf16* vT   = qkvb + (size_t)8192 * 3072;
  bf16* ob   = vT   + (size_t)8  * 1024 * 1024;

  cast3_kernel<<<2048, 256, 0, stream>>>(x, w1, w2, xb, w1b, w2b);

  // QKV: 256x384 tiles -> grid 32x8 = 256 = exactly one round (160KB LDS).
  // v-part written to vT via LDS transpose bounce (vtrans eliminated).
  gemmks_kernel<1, 2, 4, 4, 3><<<256, 512, 0, stream>>>(xb, w1b, b1, qkvb, vT,
                                                        8192, 3072, 1024, 8);
  attn_kernel<<<512, 256, 0, stream>>>(qkvb, vT, ob);
  // proj: 256x128 tiles -> grid 32x8 = 256 = exactly one round (96KB LDS).
  gemmks_kernel<0, 4, 2, 2, 2><<<256, 512, 0, stream>>>(ob, w2b, b2, out, nullptr,
                                                        8192, 1024, 1024, 8);
}